// Round 6
// baseline (321.106 us; speedup 1.0000x reference)
//
#include <hip/hip_runtime.h>
#include <stdint.h>
#include <stddef.h>

typedef unsigned short ushort_t;
typedef __bf16 bf16_t;
typedef bf16_t bf16x8 __attribute__((ext_vector_type(8)));
typedef bf16_t bf16x4 __attribute__((ext_vector_type(4)));
typedef float f32x4 __attribute__((ext_vector_type(4)));
// ALL memory accesses use may_alias vector types (uniform TBAA).
typedef unsigned short ushort2v __attribute__((ext_vector_type(2), may_alias));
typedef unsigned short ushort4v __attribute__((ext_vector_type(4), may_alias));
typedef unsigned short ushort8v __attribute__((ext_vector_type(8), may_alias));
typedef float f32x4v __attribute__((ext_vector_type(4), may_alias));

union U8 { ushort8v u; bf16x8 b; };
union U4 { ushort4v u; bf16x4 b; };

#define L2E 1.44269504088896340736f
#define SCALE_Q (0.125f * L2E)   // fold 1/sqrt(64) and log2e into Q
#define FIXED_M 12.0f            // fixed softmax max (log2 domain); scores ~20 sigma below

#define AS1 __attribute__((address_space(1)))
#define AS3 __attribute__((address_space(3)))

__device__ __forceinline__ float bf2f(ushort_t u) {
  union { unsigned int i; float f; } c; c.i = ((unsigned int)u) << 16; return c.f;
}
__device__ __forceinline__ ushort_t f2bf(float f) {  // hw RTNE cvt on gfx950
  union { bf16_t b; ushort_t u; } c; c.b = (bf16_t)f; return c.u;
}
__device__ __forceinline__ bf16x8 frag(const ushort_t* p) {
  U8 t; t.u = *(const ushort8v*)p; return t.b;
}
__device__ __forceinline__ void g2l16(const ushort_t* g, ushort_t* l) {
  __builtin_amdgcn_global_load_lds((const AS1 void*)g, (AS3 void*)l, 16, 0, 0);
}

// ---- fp32 -> bf16 bulk convert, all three tensors in one launch ----
__global__ __launch_bounds__(256)
void cvt3(const float* __restrict__ s0, ushort_t* __restrict__ d0,
          const float* __restrict__ s1, ushort_t* __restrict__ d1,
          const float* __restrict__ s2, ushort_t* __restrict__ d2)
{
  const float* s; ushort_t* d; int n4, b0, nb;
  if (blockIdx.x < 512)      { s = s0; d = d0; n4 = 1048576; b0 = 0;   nb = 512; }
  else if (blockIdx.x < 896) { s = s1; d = d1; n4 = 786432;  b0 = 512; nb = 384; }
  else                       { s = s2; d = d2; n4 = 262144;  b0 = 896; nb = 128; }
  int i = ((int)blockIdx.x - b0) * 256 + threadIdx.x;
  int stride = nb * 256;
  for (; i < n4; i += stride) {
    f32x4v v = *(const f32x4v*)&s[(size_t)i * 4];
    ushort4v o;
#pragma unroll
    for (int r = 0; r < 4; ++r) o[r] = f2bf(v[r]);
    *(ushort4v*)&d[(size_t)i * 4] = o;
  }
}

// C[M,N] = A[M,K] @ B[N,K]^T + bias (fp32).  A,B bf16.
// m97 structure: global_load_lds width-16 staging, unpadded tiles.
// TM x 128 tile, 4 waves (2x2), each wave (TM/2)x64 via (TM/32)x4 MFMA grid.
// launch_bounds(256,3): cap VGPR ~168 -> 3 blocks/CU (m97 operating point).
template <int OUT_BF16, int TM>
__global__ __launch_bounds__(256, 3)
void gemm_bt(const ushort_t* __restrict__ A, const ushort_t* __restrict__ B,
             const float* __restrict__ bias, void* __restrict__ Cp,
             int M, int N, int K, int scaleCols)
{
  __shared__ __align__(16) ushort_t a_lds[TM * 64];
  __shared__ __align__(16) ushort_t b_lds[128 * 64];
  const int t = threadIdx.x;
  const int lane = t & 63;
  const int w = t >> 6;
  const int wr = w >> 1, wc = w & 1;
  const int l15 = lane & 15, l16 = lane >> 4;
  const int mbase = blockIdx.x * TM;
  const int nbase = blockIdx.y * 128;
  const int MI = TM / 32;   // i-subtiles per wave

  // staging: wave w stages A rows [w*TM/4, +TM/4), B rows [w*32, +32); 8 rows/pass
  const int lr = lane >> 3;
  const int scol = (lane & 7) * 8;
  const ushort_t* ag = &A[(size_t)(mbase + w * (TM / 4) + lr) * K + scol];
  const ushort_t* bg = &B[(size_t)(nbase + w * 32 + lr) * K + scol];
  ushort_t* al = &a_lds[w * (TM / 4) * 64];   // wave-uniform LDS base
  ushort_t* bl = &b_lds[w * 32 * 64];
  const size_t rs8 = (size_t)8 * K;

  const f32x4 fzero = {0.f, 0.f, 0.f, 0.f};
  f32x4 acc[MI][4];
#pragma unroll
  for (int i = 0; i < MI; ++i)
#pragma unroll
    for (int j = 0; j < 4; ++j) acc[i][j] = fzero;

  for (int kk = 0; kk < K; kk += 64) {
    __syncthreads();
#pragma unroll
    for (int p = 0; p < TM / 32; ++p)
      g2l16(ag + p * rs8 + kk, al + p * 8 * 64);
#pragma unroll
    for (int p = 0; p < 4; ++p)
      g2l16(bg + p * rs8 + kk, bl + p * 8 * 64);
    __syncthreads();   // drains vmcnt: tiles resident
#pragma unroll
    for (int ks = 0; ks < 2; ++ks) {
      bf16x8 af[MI], bfr[4];
#pragma unroll
      for (int i = 0; i < MI; ++i)
        af[i] = frag(&a_lds[(wr * (TM / 2) + i * 16 + l15) * 64 + ks * 32 + l16 * 8]);
#pragma unroll
      for (int j = 0; j < 4; ++j)
        bfr[j] = frag(&b_lds[(wc * 64 + j * 16 + l15) * 64 + ks * 32 + l16 * 8]);
#pragma unroll
      for (int i = 0; i < MI; ++i)
#pragma unroll
        for (int j = 0; j < 4; ++j)
          acc[i][j] = __builtin_amdgcn_mfma_f32_16x16x32_bf16(bfr[j], af[i], acc[i][j], 0, 0, 0);
    }
  }

#pragma unroll
  for (int i = 0; i < MI; ++i) {
    int m = mbase + wr * (TM / 2) + i * 16 + l15;
#pragma unroll
    for (int j = 0; j < 4; ++j) {
      int n0 = nbase + wc * 64 + j * 16 + l16 * 4;
      f32x4v bb = *(const f32x4v*)&bias[n0];
      if (OUT_BF16) {
        float sc = (n0 < scaleCols) ? SCALE_Q : 1.0f;
        ushort4v ow;
#pragma unroll
        for (int r = 0; r < 4; ++r) ow[r] = f2bf((acc[i][j][r] + bb[r]) * sc);
        *(ushort4v*)&((ushort_t*)Cp)[(size_t)m * N + n0] = ow;
      } else {
        f32x4v ow;
#pragma unroll
        for (int r = 0; r < 4; ++r) ow[r] = acc[i][j][r] + bb[r];
        *(f32x4v*)&((float*)Cp)[(size_t)m * N + n0] = ow;
      }
    }
  }
}

// vT[h][d][s] = qkv[s][2048 + h*64 + d]  (per 128-row s-tile, LDS transpose; bf16)
__global__ __launch_bounds__(256)
void vtrans(const ushort_t* __restrict__ qkv, ushort_t* __restrict__ vT)
{
  __shared__ __align__(16) ushort_t tile[64 * 136];
  const int t = threadIdx.x;
  const int sb = blockIdx.x;  // 0..31
  const int h = blockIdx.y;   // 0..15
#pragma unroll
  for (int i = 0; i < 2; ++i) {
    int idx = t + i * 256;  // 64 s-pairs x 8 d-chunks
    int sp = idx >> 3;
    int c = idx & 7;
    const ushort_t* g0 = &qkv[(size_t)(sb * 128 + 2 * sp) * 3072 + 2048 + h * 64 + c * 8];
    ushort8v ua = *(const ushort8v*)g0;
    ushort8v ub = *(const ushort8v*)(g0 + 3072);
#pragma unroll
    for (int ii = 0; ii < 8; ++ii) {
      int dd = ii ^ c;  // xor-rotate to spread banks
      ushort2v pk;
      pk[0] = ua[dd];
      pk[1] = ub[dd];
      *(ushort2v*)&tile[(c * 8 + dd) * 136 + 2 * sp] = pk;
    }
  }
  __syncthreads();
#pragma unroll
  for (int i = 0; i < 4; ++i) {
    int idx = t + i * 256;  // 64 d-rows x 16 s-chunks
    int d = idx >> 4;
    int scn = idx & 15;
    *(ushort8v*)&vT[((size_t)(h * 64 + d)) * 4096 + sb * 128 + scn * 8] =
        *(const ushort8v*)&tile[d * 136 + scn * 8];
  }
}

// Split-KV flash attention, transposed: S^T = K*Q^T, O^T = V^T*P^T.
// Fixed-max softmax (sacc init -FIXED_M).  LDS diet for 4 blocks/CU:
// one 128x72 buffer aliases Q-stage -> K tile -> P halves (P processed in two
// 64-wide k-halves; per-wave rows, wave-local lgkm drains between phases).
// l summed in VALU from rounded P; cross-lane reduction hoisted to epilogue.
__global__ __launch_bounds__(256, 4)
void attn(const ushort_t* __restrict__ qkv, const ushort_t* __restrict__ vT,
          ushort_t* __restrict__ att, ushort_t* __restrict__ Opart,
          float* __restrict__ l_ws)
{
  __shared__ __align__(16) ushort_t kp_lds[128 * 72];   // 18.0 KB: Q / K / P halves
  __shared__ __align__(16) ushort_t vt_lds[64 * 136];   // 17.0 KB: V^T tile
  const int t = threadIdx.x;
  const int lane = t & 63;
  const int w = t >> 6;
  const int l15 = lane & 15, l16 = lane >> 4;
  // decode (qb, chunk) heavy-first
  const int u = 79 - (int)blockIdx.x;
  int qb, ci;
  if (u < 8)       { qb = u;                  ci = 0; }
  else if (u < 24) { qb = 8 + ((u - 8) >> 1);  ci = (u - 8) & 1; }
  else if (u < 48) { qb = 16 + (u - 24) / 3;   ci = (u - 24) % 3; }
  else             { qb = 24 + ((u - 48) >> 2); ci = (u - 48) & 3; }
  const int h = blockIdx.y;
  const int nc = (qb >> 3) + 1;
  const int jbeg = ci * 8;
  const int jend = min(jbeg + 8, qb + 1);

  // stage Q (pre-scaled by 0.125*log2e) into kp_lds [128][72]
#pragma unroll
  for (int i = 0; i < 4; ++i) {
    int idx = t + i * 256;
    int row = idx >> 3, c = idx & 7;
    *(ushort8v*)&kp_lds[row * 72 + c * 8] =
        *(const ushort8v*)&qkv[(size_t)(qb * 128 + row) * 3072 + h * 64 + c * 8];
  }
  __syncthreads();
  bf16x8 qf[2][2];  // wave-local rows; barrier A of iter 0 orders vs K overwrite
#pragma unroll
  for (int nq = 0; nq < 2; ++nq)
#pragma unroll
    for (int ks = 0; ks < 2; ++ks)
      qf[nq][ks] = frag(&kp_lds[(w * 32 + nq * 16 + l15) * 72 + ks * 32 + l16 * 8]);

  const f32x4 fzero = {0.f, 0.f, 0.f, 0.f};
  f32x4 o[4][2];
#pragma unroll
  for (int di = 0; di < 4; ++di)
#pragma unroll
    for (int nq = 0; nq < 2; ++nq) o[di][nq] = fzero;
  float l_i[2] = {0.f, 0.f};

  // register prefetch mapping for K (128x64) and V^T (64x128) tiles
  const int krow0 = t >> 3, kcol = (t & 7) * 8;
  const int vd0 = t >> 4, vs = (t & 15) * 8;
  const ushort_t* kg = &qkv[(size_t)krow0 * 3072 + 1024 + h * 64 + kcol];
  const ushort_t* vg = &vT[((size_t)(h * 64 + vd0)) * 4096 + vs];
  ushort8v kr[4], vr[4];
  {
    const ushort_t* kgj = kg + (size_t)jbeg * 128 * 3072;
    const ushort_t* vgj = vg + (size_t)jbeg * 128;
#pragma unroll
    for (int c = 0; c < 4; ++c) {
      kr[c] = *(const ushort8v*)(kgj + (size_t)c * 32 * 3072);
      vr[c] = *(const ushort8v*)(vgj + (size_t)c * 16 * 4096);
    }
  }

  for (int j = jbeg; j < jend; ++j) {
    __syncthreads();  // A: all waves done reading P (kp) and vt of prev iter
#pragma unroll
    for (int c = 0; c < 4; ++c) {
      *(ushort8v*)&kp_lds[(krow0 + c * 32) * 72 + kcol] = kr[c];
      *(ushort8v*)&vt_lds[(vd0 + c * 16) * 136 + vs] = vr[c];
    }
    __syncthreads();  // B: tiles visible
    if (j + 1 < jend) {
      const ushort_t* kgj = kg + (size_t)(j + 1) * 128 * 3072;
      const ushort_t* vgj = vg + (size_t)(j + 1) * 128;
#pragma unroll
      for (int c = 0; c < 4; ++c) {
        kr[c] = *(const ushort8v*)(kgj + (size_t)c * 32 * 3072);
        vr[c] = *(const ushort8v*)(vgj + (size_t)c * 16 * 4096);
      }
    }

    // S^T tile, accumulator pre-loaded with -FIXED_M
    f32x4 sacc[8][2];
#pragma unroll
    for (int ki = 0; ki < 8; ++ki)
#pragma unroll
      for (int nq = 0; nq < 2; ++nq) {
        f32x4 mi = {-FIXED_M, -FIXED_M, -FIXED_M, -FIXED_M};
        sacc[ki][nq] = mi;
      }
#pragma unroll
    for (int ki = 0; ki < 8; ++ki) {
      bf16x8 kf0 = frag(&kp_lds[(ki * 16 + l15) * 72 + l16 * 8]);
      bf16x8 kf1 = frag(&kp_lds[(ki * 16 + l15) * 72 + 32 + l16 * 8]);
#pragma unroll
      for (int nq = 0; nq < 2; ++nq) {
        sacc[ki][nq] = __builtin_amdgcn_mfma_f32_16x16x32_bf16(kf0, qf[nq][0], sacc[ki][nq], 0, 0, 0);
        sacc[ki][nq] = __builtin_amdgcn_mfma_f32_16x16x32_bf16(kf1, qf[nq][1], sacc[ki][nq], 0, 0, 0);
      }
    }
    __syncthreads();  // C: all K reads complete; kp region free for P

#pragma unroll
    for (int half = 0; half < 2; ++half) {
      // WAR: this wave's pf reads of previous half must be retired before
      // overwriting; lgkmcnt(0) drains them (DS ops are per-wave tracked).
      asm volatile("s_waitcnt lgkmcnt(0)" ::: "memory");
#pragma unroll
      for (int nq = 0; nq < 2; ++nq)
#pragma unroll
        for (int k2 = 0; k2 < 4; ++k2) {
          int ki = half * 4 + k2;
          U4 pc;
#pragma unroll
          for (int r = 0; r < 4; ++r)
            pc.b[r] = (bf16_t)__builtin_amdgcn_exp2f(sacc[ki][nq][r]);
          *(ushort4v*)&kp_lds[(w * 32 + nq * 16 + l15) * 72 + k2 * 16 + l16 * 4] = pc.u;
#pragma unroll
          for (int r = 0; r < 4; ++r)
            l_i[nq] += (float)pc.b[r];   // denominator == rounded numerator
        }
      asm volatile("s_waitcnt lgkmcnt(0)" ::: "memory");  // P visible to own wave
#pragma unroll
      for (int ksl = 0; ksl < 2; ++ksl) {
        bf16x8 pf[2];
#pragma unroll
        for (int nq = 0; nq < 2; ++nq)
          pf[nq] = frag(&kp_lds[(w * 32 + nq * 16 + l15) * 72 + ksl * 32 + l16 * 8]);
#pragma unroll
        for (int di = 0; di < 4; ++di) {
          bf16x8 vf = frag(&vt_lds[(di * 16 + l15) * 136 + half * 64 + ksl * 32 + l16 * 8]);
#pragma unroll
          for (int nq = 0; nq < 2; ++nq)
            o[di][nq] = __builtin_amdgcn_mfma_f32_16x16x32_bf16(vf, pf[nq], o[di][nq], 0, 0, 0);
        }
      }
    }
  }

  // reduce l across the 4 l16 groups (once, not per iter)
#pragma unroll
  for (int nq = 0; nq < 2; ++nq) {
    l_i[nq] += __shfl_xor(l_i[nq], 16, 64);
    l_i[nq] += __shfl_xor(l_i[nq], 32, 64);
  }

  if (nc == 1) {
#pragma unroll
    for (int nq = 0; nq < 2; ++nq) {
      float rl = 1.0f / l_i[nq];
      int q = qb * 128 + w * 32 + nq * 16 + l15;
#pragma unroll
      for (int di = 0; di < 4; ++di) {
        ushort4v ow;
#pragma unroll
        for (int r = 0; r < 4; ++r) ow[r] = f2bf(o[di][nq][r] * rl);
        *(ushort4v*)&att[(size_t)q * 1024 + h * 64 + di * 16 + l16 * 4] = ow;
      }
    }
  } else {
    const int slot = (h * 32 + qb) * 4 + ci;
    ushort_t* ob = Opart + (size_t)slot * (128 * 64);
#pragma unroll
    for (int nq = 0; nq < 2; ++nq) {
      int q = w * 32 + nq * 16 + l15;
#pragma unroll
      for (int di = 0; di < 4; ++di) {
        ushort4v ow;
#pragma unroll
        for (int r = 0; r < 4; ++r) ow[r] = f2bf(o[di][nq][r]);
        *(ushort4v*)&ob[q * 64 + di * 16 + l16 * 4] = ow;
      }
      if (l16 == 0) l_ws[(size_t)slot * 128 + q] = l_i[nq];
    }
  }
}

// merge <=4 partials per (qb>=8, h): fixed-max -> pure sums.
__global__ __launch_bounds__(256)
void combine(const ushort_t* __restrict__ Opart, const float* __restrict__ l_ws,
             ushort_t* __restrict__ att)
{
  const int qb = 8 + (int)blockIdx.x;   // 8..31
  const int h = blockIdx.y;
  const int nc = (qb >> 3) + 1;         // 2..4
  const int t = threadIdx.x;
  const int q = t >> 1;                 // 0..127
  const int d0 = (t & 1) * 32;
  const int base_slot = (h * 32 + qb) * 4;

  float lsum = 0.f;
  for (int i = 0; i < nc; ++i) lsum += l_ws[(size_t)(base_slot + i) * 128 + q];
  float inv = 1.0f / lsum;

  float acc[32];
#pragma unroll
  for (int r = 0; r < 32; ++r) acc[r] = 0.f;
  for (int i = 0; i < nc; ++i) {
    const ushort_t* ob = &Opart[(size_t)(base_slot + i) * (128 * 64) + q * 64 + d0];
#pragma unroll
    for (int c = 0; c < 4; ++c) {
      ushort8v v = *(const ushort8v*)&ob[c * 8];
#pragma unroll
      for (int r = 0; r < 8; ++r) acc[c * 8 + r] += bf2f(v[r]);
    }
  }
  const size_t qg = (size_t)(qb * 128 + q);
#pragma unroll
  for (int c = 0; c < 4; ++c) {
    ushort8v ov;
#pragma unroll
    for (int r = 0; r < 8; ++r) ov[r] = f2bf(acc[c * 8 + r] * inv);
    *(ushort8v*)&att[qg * 1024 + h * 64 + d0 + c * 8] = ov;
  }
}

extern "C" void kernel_launch(void* const* d_in, const int* in_sizes, int n_in,
                              void* d_out, int out_size, void* d_ws, size_t ws_size,
                              hipStream_t stream) {
  const float* x     = (const float*)d_in[0];  // [4096,1024] fp32
  const float* w_in  = (const float*)d_in[1];  // [3072,1024] fp32
  const float* b_in  = (const float*)d_in[2];  // [3072] fp32
  const float* w_out = (const float*)d_in[3];  // [1024,1024] fp32
  const float* b_out = (const float*)d_in[4];  // [1024] fp32

  // workspace layout (bf16 elements unless noted); total ~90.5 MB
  ushort_t* qkv   = (ushort_t*)d_ws;                     // 4096*3072
  ushort_t* vT    = qkv + (size_t)4096 * 3072;           // 16*64*4096
  ushort_t* att   = vT + (size_t)16 * 64 * 4096;         // 4096*1024
  ushort_t* xb    = att + (size_t)4096 * 1024;           // 4096*1024
  ushort_t* wib   = xb + (size_t)4096 * 1024;            // 3072*1024
  ushort_t* wob   = wib + (size_t)3072 * 1024;           // 1024*1024
  ushort_t* Opart = wob + (size_t)1024 * 1024;           // 2048 * 128*64
  float*    l_ws  = (float*)(Opart + (size_t)2048 * 128 * 64);  // 2048*128 fp32

  // fp32 -> bf16, all three tensors in one launch
  cvt3<<<1024, 256, 0, stream>>>(x, xb, w_in, wib, w_out, wob);

  // QKV projection (+fp32 bias; Q cols scaled by 0.125*log2e), bf16 out
  gemm_bt<1, 128><<<dim3(32, 24), 256, 0, stream>>>(xb, wib, b_in, qkv, 4096, 3072, 1024, 1024);
  // V^T for attention B-operand
  vtrans<<<dim3(32, 16), 256, 0, stream>>>(qkv, vT);
  // split-KV block-causal flash attention (1280 balanced blocks, 4 blocks/CU)
  attn<<<dim3(80, 16), 256, 0, stream>>>(qkv, vT, att, Opart, l_ws);
  // merge partials for qb>=8 (pure sums under fixed-max)
  combine<<<dim3(24, 16), 256, 0, stream>>>(Opart, l_ws, att);
  // output projection: 64x128 tiles (512 blocks), bf16 A/B, fp32 bias/out
  gemm_bt<0, 64><<<dim3(64, 8), 256, 0, stream>>>(att, wob, b_out, d_out, 4096, 1024, 1024, 0);
}

// Round 7
// 224.374 us; speedup vs baseline: 1.4311x; 1.4311x over previous
//
#include <hip/hip_runtime.h>
#include <stdint.h>
#include <stddef.h>

typedef unsigned short ushort_t;
typedef __bf16 bf16_t;
typedef bf16_t bf16x8 __attribute__((ext_vector_type(8)));
typedef bf16_t bf16x4 __attribute__((ext_vector_type(4)));
typedef float f32x4 __attribute__((ext_vector_type(4)));
// ALL memory accesses use may_alias vector types (uniform TBAA).
typedef unsigned short ushort2v __attribute__((ext_vector_type(2), may_alias));
typedef unsigned short ushort4v __attribute__((ext_vector_type(4), may_alias));
typedef unsigned short ushort8v __attribute__((ext_vector_type(8), may_alias));
typedef float f32x4v __attribute__((ext_vector_type(4), may_alias));

union U8 { ushort8v u; bf16x8 b; };
union U4 { ushort4v u; bf16x4 b; };

#define L2E 1.44269504088896340736f
#define SCALE_Q (0.125f * L2E)   // fold 1/sqrt(64) and log2e into Q
#define FIXED_M 12.0f            // fixed softmax max (log2 domain); scores ~20 sigma below

#define AS1 __attribute__((address_space(1)))
#define AS3 __attribute__((address_space(3)))

__device__ __forceinline__ float bf2f(ushort_t u) {
  union { unsigned int i; float f; } c; c.i = ((unsigned int)u) << 16; return c.f;
}
__device__ __forceinline__ ushort_t f2bf(float f) {  // hw RTNE cvt on gfx950
  union { bf16_t b; ushort_t u; } c; c.b = (bf16_t)f; return c.u;
}
__device__ __forceinline__ bf16x8 frag(const ushort_t* p) {
  U8 t; t.u = *(const ushort8v*)p; return t.b;
}
__device__ __forceinline__ void g2l16(const ushort_t* g, ushort_t* l) {
  __builtin_amdgcn_global_load_lds((const AS1 void*)g, (AS3 void*)l, 16, 0, 0);
}

// ---- fp32 -> bf16 bulk convert, all three tensors in one launch ----
__global__ __launch_bounds__(256)
void cvt3(const float* __restrict__ s0, ushort_t* __restrict__ d0,
          const float* __restrict__ s1, ushort_t* __restrict__ d1,
          const float* __restrict__ s2, ushort_t* __restrict__ d2)
{
  const float* s; ushort_t* d; int n4, b0, nb;
  if (blockIdx.x < 512)      { s = s0; d = d0; n4 = 1048576; b0 = 0;   nb = 512; }
  else if (blockIdx.x < 896) { s = s1; d = d1; n4 = 786432;  b0 = 512; nb = 384; }
  else                       { s = s2; d = d2; n4 = 262144;  b0 = 896; nb = 128; }
  int i = ((int)blockIdx.x - b0) * 256 + threadIdx.x;
  int stride = nb * 256;
  for (; i < n4; i += stride) {
    f32x4v v = *(const f32x4v*)&s[(size_t)i * 4];
    ushort4v o;
#pragma unroll
    for (int r = 0; r < 4; ++r) o[r] = f2bf(v[r]);
    *(ushort4v*)&d[(size_t)i * 4] = o;
  }
}

// C[M,N] = A[M,K] @ B[N,K]^T + bias (fp32).  A,B bf16.
// m97 structure: global_load_lds width-16 staging, unpadded tiles.
// TM x 128 tile, 4 waves (2x2), each wave (TM/2)x64 via (TM/32)x4 MFMA grid.
template <int OUT_BF16, int TM>
__global__ __launch_bounds__(256, 3)
void gemm_bt(const ushort_t* __restrict__ A, const ushort_t* __restrict__ B,
             const float* __restrict__ bias, void* __restrict__ Cp,
             int M, int N, int K, int scaleCols)
{
  __shared__ __align__(16) ushort_t a_lds[TM * 64];
  __shared__ __align__(16) ushort_t b_lds[128 * 64];
  const int t = threadIdx.x;
  const int lane = t & 63;
  const int w = t >> 6;
  const int wr = w >> 1, wc = w & 1;
  const int l15 = lane & 15, l16 = lane >> 4;
  const int mbase = blockIdx.x * TM;
  const int nbase = blockIdx.y * 128;
  const int MI = TM / 32;   // i-subtiles per wave

  // staging: wave w stages A rows [w*TM/4, +TM/4), B rows [w*32, +32); 8 rows/pass
  const int lr = lane >> 3;
  const int scol = (lane & 7) * 8;
  const ushort_t* ag = &A[(size_t)(mbase + w * (TM / 4) + lr) * K + scol];
  const ushort_t* bg = &B[(size_t)(nbase + w * 32 + lr) * K + scol];
  ushort_t* al = &a_lds[w * (TM / 4) * 64];   // wave-uniform LDS base
  ushort_t* bl = &b_lds[w * 32 * 64];
  const size_t rs8 = (size_t)8 * K;

  const f32x4 fzero = {0.f, 0.f, 0.f, 0.f};
  f32x4 acc[MI][4];
#pragma unroll
  for (int i = 0; i < MI; ++i)
#pragma unroll
    for (int j = 0; j < 4; ++j) acc[i][j] = fzero;

  for (int kk = 0; kk < K; kk += 64) {
    __syncthreads();
#pragma unroll
    for (int p = 0; p < TM / 32; ++p)
      g2l16(ag + p * rs8 + kk, al + p * 8 * 64);
#pragma unroll
    for (int p = 0; p < 4; ++p)
      g2l16(bg + p * rs8 + kk, bl + p * 8 * 64);
    __syncthreads();   // drains vmcnt: tiles resident
#pragma unroll
    for (int ks = 0; ks < 2; ++ks) {
      bf16x8 af[MI], bfr[4];
#pragma unroll
      for (int i = 0; i < MI; ++i)
        af[i] = frag(&a_lds[(wr * (TM / 2) + i * 16 + l15) * 64 + ks * 32 + l16 * 8]);
#pragma unroll
      for (int j = 0; j < 4; ++j)
        bfr[j] = frag(&b_lds[(wc * 64 + j * 16 + l15) * 64 + ks * 32 + l16 * 8]);
#pragma unroll
      for (int i = 0; i < MI; ++i)
#pragma unroll
        for (int j = 0; j < 4; ++j)
          acc[i][j] = __builtin_amdgcn_mfma_f32_16x16x32_bf16(bfr[j], af[i], acc[i][j], 0, 0, 0);
    }
  }

#pragma unroll
  for (int i = 0; i < MI; ++i) {
    int m = mbase + wr * (TM / 2) + i * 16 + l15;
#pragma unroll
    for (int j = 0; j < 4; ++j) {
      int n0 = nbase + wc * 64 + j * 16 + l16 * 4;
      f32x4v bb = *(const f32x4v*)&bias[n0];
      if (OUT_BF16) {
        float sc = (n0 < scaleCols) ? SCALE_Q : 1.0f;
        ushort4v ow;
#pragma unroll
        for (int r = 0; r < 4; ++r) ow[r] = f2bf((acc[i][j][r] + bb[r]) * sc);
        *(ushort4v*)&((ushort_t*)Cp)[(size_t)m * N + n0] = ow;
      } else {
        f32x4v ow;
#pragma unroll
        for (int r = 0; r < 4; ++r) ow[r] = acc[i][j][r] + bb[r];
        *(f32x4v*)&((float*)Cp)[(size_t)m * N + n0] = ow;
      }
    }
  }
}

// vT[h][d][s] = qkv[s][2048 + h*64 + d]  (per 128-row s-tile, LDS transpose; bf16)
__global__ __launch_bounds__(256)
void vtrans(const ushort_t* __restrict__ qkv, ushort_t* __restrict__ vT)
{
  __shared__ __align__(16) ushort_t tile[64 * 136];
  const int t = threadIdx.x;
  const int sb = blockIdx.x;  // 0..31
  const int h = blockIdx.y;   // 0..15
#pragma unroll
  for (int i = 0; i < 2; ++i) {
    int idx = t + i * 256;  // 64 s-pairs x 8 d-chunks
    int sp = idx >> 3;
    int c = idx & 7;
    const ushort_t* g0 = &qkv[(size_t)(sb * 128 + 2 * sp) * 3072 + 2048 + h * 64 + c * 8];
    ushort8v ua = *(const ushort8v*)g0;
    ushort8v ub = *(const ushort8v*)(g0 + 3072);
#pragma unroll
    for (int ii = 0; ii < 8; ++ii) {
      int dd = ii ^ c;  // xor-rotate to spread banks
      ushort2v pk;
      pk[0] = ua[dd];
      pk[1] = ub[dd];
      *(ushort2v*)&tile[(c * 8 + dd) * 136 + 2 * sp] = pk;
    }
  }
  __syncthreads();
#pragma unroll
  for (int i = 0; i < 4; ++i) {
    int idx = t + i * 256;  // 64 d-rows x 16 s-chunks
    int d = idx >> 4;
    int scn = idx & 15;
    *(ushort8v*)&vT[((size_t)(h * 64 + d)) * 4096 + sb * 128 + scn * 8] =
        *(const ushort8v*)&tile[d * 136 + scn * 8];
  }
}

// Split-KV flash attention, transposed: S^T = K*Q^T, O^T = V^T*P^T.
// Fixed-max softmax (sacc init -FIXED_M).  S-phase halved (sacc 32 regs not
// 64) so true demand ~155 regs fits launch_bounds(256,3) cap (~170): r6's
// (256,4) spilled 420 MB to scratch.  P has its own buffer (K stays live;
// only 2 barriers/iter).  LDS 53 KB -> 3 blocks/CU.
__global__ __launch_bounds__(256, 3)
void attn(const ushort_t* __restrict__ qkv, const ushort_t* __restrict__ vT,
          ushort_t* __restrict__ att, ushort_t* __restrict__ Opart,
          float* __restrict__ l_ws)
{
  __shared__ __align__(16) ushort_t k_lds[128 * 72];    // 18 KB: K tile
  __shared__ __align__(16) ushort_t p_lds[128 * 72];    // 18 KB: Q stage, then P halves
  __shared__ __align__(16) ushort_t vt_lds[64 * 136];   // 17 KB: V^T tile
  const int t = threadIdx.x;
  const int lane = t & 63;
  const int w = t >> 6;
  const int l15 = lane & 15, l16 = lane >> 4;
  // decode (qb, chunk) heavy-first
  const int u = 79 - (int)blockIdx.x;
  int qb, ci;
  if (u < 8)       { qb = u;                  ci = 0; }
  else if (u < 24) { qb = 8 + ((u - 8) >> 1);  ci = (u - 8) & 1; }
  else if (u < 48) { qb = 16 + (u - 24) / 3;   ci = (u - 24) % 3; }
  else             { qb = 24 + ((u - 48) >> 2); ci = (u - 48) & 3; }
  const int h = blockIdx.y;
  const int nc = (qb >> 3) + 1;
  const int jbeg = ci * 8;
  const int jend = min(jbeg + 8, qb + 1);

  // stage Q (pre-scaled by 0.125*log2e) into p_lds [128][72]
#pragma unroll
  for (int i = 0; i < 4; ++i) {
    int idx = t + i * 256;
    int row = idx >> 3, c = idx & 7;
    *(ushort8v*)&p_lds[row * 72 + c * 8] =
        *(const ushort8v*)&qkv[(size_t)(qb * 128 + row) * 3072 + h * 64 + c * 8];
  }
  __syncthreads();
  // qf reads + later P writes touch only this wave's rows [w*32, w*32+32):
  // all p_lds hazards after this point are wave-local (lgkm drains suffice).
  bf16x8 qf[2][2];
#pragma unroll
  for (int nq = 0; nq < 2; ++nq)
#pragma unroll
    for (int ks = 0; ks < 2; ++ks)
      qf[nq][ks] = frag(&p_lds[(w * 32 + nq * 16 + l15) * 72 + ks * 32 + l16 * 8]);

  const f32x4 fzero = {0.f, 0.f, 0.f, 0.f};
  f32x4 o[4][2];
#pragma unroll
  for (int di = 0; di < 4; ++di)
#pragma unroll
    for (int nq = 0; nq < 2; ++nq) o[di][nq] = fzero;
  float l_i[2] = {0.f, 0.f};

  // register prefetch mapping for K (128x64) and V^T (64x128) tiles
  const int krow0 = t >> 3, kcol = (t & 7) * 8;
  const int vd0 = t >> 4, vs = (t & 15) * 8;
  const ushort_t* kg = &qkv[(size_t)krow0 * 3072 + 1024 + h * 64 + kcol];
  const ushort_t* vg = &vT[((size_t)(h * 64 + vd0)) * 4096 + vs];
  ushort8v kr[4], vr[4];
  {
    const ushort_t* kgj = kg + (size_t)jbeg * 128 * 3072;
    const ushort_t* vgj = vg + (size_t)jbeg * 128;
#pragma unroll
    for (int c = 0; c < 4; ++c) {
      kr[c] = *(const ushort8v*)(kgj + (size_t)c * 32 * 3072);
      vr[c] = *(const ushort8v*)(vgj + (size_t)c * 16 * 4096);
    }
  }

  for (int j = jbeg; j < jend; ++j) {
    __syncthreads();  // A: all waves done reading K/V of prev iter
#pragma unroll
    for (int c = 0; c < 4; ++c) {
      *(ushort8v*)&k_lds[(krow0 + c * 32) * 72 + kcol] = kr[c];
      *(ushort8v*)&vt_lds[(vd0 + c * 16) * 136 + vs] = vr[c];
    }
    __syncthreads();  // B: tiles visible
    if (j + 1 < jend) {  // prefetch next tiles; whole compute phase hides latency
      const ushort_t* kgj = kg + (size_t)(j + 1) * 128 * 3072;
      const ushort_t* vgj = vg + (size_t)(j + 1) * 128;
#pragma unroll
      for (int c = 0; c < 4; ++c) {
        kr[c] = *(const ushort8v*)(kgj + (size_t)c * 32 * 3072);
        vr[c] = *(const ushort8v*)(vgj + (size_t)c * 16 * 4096);
      }
    }

    // two half-phases: S(4 ki) -> exp2 -> P -> PV   (sacc = 32 regs, not 64)
#pragma unroll
    for (int half = 0; half < 2; ++half) {
      f32x4 sacc[4][2];
#pragma unroll
      for (int k2 = 0; k2 < 4; ++k2)
#pragma unroll
        for (int nq = 0; nq < 2; ++nq) {
          f32x4 mi = {-FIXED_M, -FIXED_M, -FIXED_M, -FIXED_M};
          sacc[k2][nq] = mi;
        }
#pragma unroll
      for (int k2 = 0; k2 < 4; ++k2) {
        int ki = half * 4 + k2;
        bf16x8 kf0 = frag(&k_lds[(ki * 16 + l15) * 72 + l16 * 8]);
        bf16x8 kf1 = frag(&k_lds[(ki * 16 + l15) * 72 + 32 + l16 * 8]);
#pragma unroll
        for (int nq = 0; nq < 2; ++nq) {
          sacc[k2][nq] = __builtin_amdgcn_mfma_f32_16x16x32_bf16(kf0, qf[nq][0], sacc[k2][nq], 0, 0, 0);
          sacc[k2][nq] = __builtin_amdgcn_mfma_f32_16x16x32_bf16(kf1, qf[nq][1], sacc[k2][nq], 0, 0, 0);
        }
      }

      // WAR: this wave's pf reads of the previous half must retire first
      asm volatile("s_waitcnt lgkmcnt(0)" ::: "memory");
#pragma unroll
      for (int nq = 0; nq < 2; ++nq)
#pragma unroll
        for (int k2 = 0; k2 < 4; ++k2) {
          U4 pc;
#pragma unroll
          for (int r = 0; r < 4; ++r)
            pc.b[r] = (bf16_t)__builtin_amdgcn_exp2f(sacc[k2][nq][r]);
          *(ushort4v*)&p_lds[(w * 32 + nq * 16 + l15) * 72 + k2 * 16 + l16 * 4] = pc.u;
#pragma unroll
          for (int r = 0; r < 4; ++r)
            l_i[nq] += (float)pc.b[r];   // denominator == rounded numerator
        }
      asm volatile("s_waitcnt lgkmcnt(0)" ::: "memory");  // P visible to own wave

#pragma unroll
      for (int ksl = 0; ksl < 2; ++ksl) {
        bf16x8 pf[2];
#pragma unroll
        for (int nq = 0; nq < 2; ++nq)
          pf[nq] = frag(&p_lds[(w * 32 + nq * 16 + l15) * 72 + ksl * 32 + l16 * 8]);
#pragma unroll
        for (int di = 0; di < 4; ++di) {
          bf16x8 vf = frag(&vt_lds[(di * 16 + l15) * 136 + half * 64 + ksl * 32 + l16 * 8]);
#pragma unroll
          for (int nq = 0; nq < 2; ++nq)
            o[di][nq] = __builtin_amdgcn_mfma_f32_16x16x32_bf16(vf, pf[nq], o[di][nq], 0, 0, 0);
        }
      }
    }
  }

  // reduce l across the 4 l16 groups (once, not per iter)
#pragma unroll
  for (int nq = 0; nq < 2; ++nq) {
    l_i[nq] += __shfl_xor(l_i[nq], 16, 64);
    l_i[nq] += __shfl_xor(l_i[nq], 32, 64);
  }

  if (nc == 1) {
#pragma unroll
    for (int nq = 0; nq < 2; ++nq) {
      float rl = 1.0f / l_i[nq];
      int q = qb * 128 + w * 32 + nq * 16 + l15;
#pragma unroll
      for (int di = 0; di < 4; ++di) {
        ushort4v ow;
#pragma unroll
        for (int r = 0; r < 4; ++r) ow[r] = f2bf(o[di][nq][r] * rl);
        *(ushort4v*)&att[(size_t)q * 1024 + h * 64 + di * 16 + l16 * 4] = ow;
      }
    }
  } else {
    const int slot = (h * 32 + qb) * 4 + ci;
    ushort_t* ob = Opart + (size_t)slot * (128 * 64);
#pragma unroll
    for (int nq = 0; nq < 2; ++nq) {
      int q = w * 32 + nq * 16 + l15;
#pragma unroll
      for (int di = 0; di < 4; ++di) {
        ushort4v ow;
#pragma unroll
        for (int r = 0; r < 4; ++r) ow[r] = f2bf(o[di][nq][r]);
        *(ushort4v*)&ob[q * 64 + di * 16 + l16 * 4] = ow;
      }
      if (l16 == 0) l_ws[(size_t)slot * 128 + q] = l_i[nq];
    }
  }
}

// merge <=4 partials per (qb>=8, h): fixed-max -> pure sums.
__global__ __launch_bounds__(256)
void combine(const ushort_t* __restrict__ Opart, const float* __restrict__ l_ws,
             ushort_t* __restrict__ att)
{
  const int qb = 8 + (int)blockIdx.x;   // 8..31
  const int h = blockIdx.y;
  const int nc = (qb >> 3) + 1;         // 2..4
  const int t = threadIdx.x;
  const int q = t >> 1;                 // 0..127
  const int d0 = (t & 1) * 32;
  const int base_slot = (h * 32 + qb) * 4;

  float lsum = 0.f;
  for (int i = 0; i < nc; ++i) lsum += l_ws[(size_t)(base_slot + i) * 128 + q];
  float inv = 1.0f / lsum;

  float acc[32];
#pragma unroll
  for (int r = 0; r < 32; ++r) acc[r] = 0.f;
  for (int i = 0; i < nc; ++i) {
    const ushort_t* ob = &Opart[(size_t)(base_slot + i) * (128 * 64) + q * 64 + d0];
#pragma unroll
    for (int c = 0; c < 4; ++c) {
      ushort8v v = *(const ushort8v*)&ob[c * 8];
#pragma unroll
      for (int r = 0; r < 8; ++r) acc[c * 8 + r] += bf2f(v[r]);
    }
  }
  const size_t qg = (size_t)(qb * 128 + q);
#pragma unroll
  for (int c = 0; c < 4; ++c) {
    ushort8v ov;
#pragma unroll
    for (int r = 0; r < 8; ++r) ov[r] = f2bf(acc[c * 8 + r] * inv);
    *(ushort8v*)&att[qg * 1024 + h * 64 + d0 + c * 8] = ov;
  }
}

extern "C" void kernel_launch(void* const* d_in, const int* in_sizes, int n_in,
                              void* d_out, int out_size, void* d_ws, size_t ws_size,
                              hipStream_t stream) {
  const float* x     = (const float*)d_in[0];  // [4096,1024] fp32
  const float* w_in  = (const float*)d_in[1];  // [3072,1024] fp32
  const float* b_in  = (const float*)d_in[2];  // [3072] fp32
  const float* w_out = (const float*)d_in[3];  // [1024,1024] fp32
  const float* b_out = (const float*)d_in[4];  // [1024] fp32

  // workspace layout (bf16 elements unless noted); total ~90.5 MB
  ushort_t* qkv   = (ushort_t*)d_ws;                     // 4096*3072
  ushort_t* vT    = qkv + (size_t)4096 * 3072;           // 16*64*4096
  ushort_t* att   = vT + (size_t)16 * 64 * 4096;         // 4096*1024
  ushort_t* xb    = att + (size_t)4096 * 1024;           // 4096*1024
  ushort_t* wib   = xb + (size_t)4096 * 1024;            // 3072*1024
  ushort_t* wob   = wib + (size_t)3072 * 1024;           // 1024*1024
  ushort_t* Opart = wob + (size_t)1024 * 1024;           // 2048 * 128*64
  float*    l_ws  = (float*)(Opart + (size_t)2048 * 128 * 64);  // 2048*128 fp32

  // fp32 -> bf16, all three tensors in one launch
  cvt3<<<1024, 256, 0, stream>>>(x, xb, w_in, wib, w_out, wob);

  // QKV projection (+fp32 bias; Q cols scaled by 0.125*log2e), bf16 out
  gemm_bt<1, 128><<<dim3(32, 24), 256, 0, stream>>>(xb, wib, b_in, qkv, 4096, 3072, 1024, 1024);
  // V^T for attention B-operand
  vtrans<<<dim3(32, 16), 256, 0, stream>>>(qkv, vT);
  // split-KV block-causal flash attention (1280 balanced blocks, 3 blocks/CU)
  attn<<<dim3(80, 16), 256, 0, stream>>>(qkv, vT, att, Opart, l_ws);
  // merge partials for qb>=8 (pure sums under fixed-max)
  combine<<<dim3(24, 16), 256, 0, stream>>>(Opart, l_ws, att);
  // output projection: 64x128 tiles (512 blocks), bf16 A/B, fp32 bias/out
  gemm_bt<0, 64><<<dim3(64, 8), 256, 0, stream>>>(att, wob, b_out, d_out, 4096, 1024, 1024, 0);
}